// Round 16
// baseline (148.908 us; speedup 1.0000x reference)
//
#include <hip/hip_runtime.h>

// Integrator (scaling & squaring) for vel [16,2,512,512] f32, with logdet-Jacobian.
// ROUND-16: LDS time-tiled STEP-PAIR fusion on the decoupled schedule with packed
// f16x4 records rec=(disp.y, disp.x, ldjac, 0).
//   pair kernel: load ext tile -> LDS, step k on (core+R2 margin) -> LDS MID,
//   __syncthreads, step k+1 on core from MID, write out. Block-local only
//   (no grid sync, no recompute). Halo sizes from the hard bound
//   max|disp_k| <= 2^k*eps*max|v| (see analysis): P1/P2 R1=R2=2, P3 R1=3,R2=4.
// 5 dispatches: INIT_FUSED -> P1(K2K3) -> P2(K4K5) -> P3(K6K7) -> FINAL.
// Buffers: rA = d_out raw (32MB), rB = ws. init->A, P1:A->B, P2:B->A, P3:A->B,
// FINAL: B -> planar f32 d_out (no aliasing: B=ws).

#define NB 16
#define HH 512
#define WW 512
#define HW (HH * WW)          // 262144 = 1<<18
#define TOT (NB * HW)         // 4194304
#define EPS 0.0078125f        // 2^-7
#define DISP_ELEMS (NB * 2 * HW)
#define SC (512.0f / 511.0f)

typedef _Float16 f16;
typedef _Float16 f16x4 __attribute__((ext_vector_type(4)));

struct SampC {
    int yc0, xc0, yc1, xc1;   // clamped corner coords (global)
    float w00, w01, w10, w11; // bilinear weights, OOB folded to 0
};

__device__ __forceinline__ SampC make_sampc(float sy, float sx) {
    float fy = floorf(sy), fx = floorf(sx);
    float wy = sy - fy, wx = sx - fx;
    int y0 = (int)fy, x0 = (int)fx;
    int y1 = y0 + 1, x1 = x0 + 1;
    bool xv0 = (unsigned)x0 < (unsigned)WW;
    bool xv1 = (unsigned)x1 < (unsigned)WW;
    bool yv0 = (unsigned)y0 < (unsigned)HH;
    bool yv1 = (unsigned)y1 < (unsigned)HH;
    SampC s;
    s.xc0 = min(max(x0, 0), WW - 1); s.xc1 = min(max(x1, 0), WW - 1);
    s.yc0 = min(max(y0, 0), HH - 1); s.yc1 = min(max(y1, 0), HH - 1);
    float omwx = 1.0f - wx, omwy = 1.0f - wy;
    s.w00 = (xv0 && yv0) ? omwx * omwy : 0.0f;
    s.w01 = (xv1 && yv0) ? wx * omwy   : 0.0f;
    s.w10 = (xv0 && yv1) ? omwx * wy   : 0.0f;
    s.w11 = (xv1 && yv1) ? wx * wy     : 0.0f;
    return s;
}

__device__ __forceinline__ f16x4 step_rec(f16x4 rv, f16x4 g00, f16x4 g01,
                                          f16x4 g10, f16x4 g11, const SampC& s) {
    float d0 = (float)rv.x, d1 = (float)rv.y, l = (float)rv.z;
    float nd0 = d0 + s.w00 * (float)g00.x + s.w01 * (float)g01.x
                   + s.w10 * (float)g10.x + s.w11 * (float)g11.x;
    float nd1 = d1 + s.w00 * (float)g00.y + s.w01 * (float)g01.y
                   + s.w10 * (float)g10.y + s.w11 * (float)g11.y;
    float nl  = l  + s.w00 * (float)g00.z + s.w01 * (float)g01.z
                   + s.w10 * (float)g10.z + s.w11 * (float)g11.z;
    f16x4 w; w.x = (f16)nd0; w.y = (f16)nd1; w.z = (f16)nl; w.w = (f16)0.0f;
    return w;
}

// XCD-remapped index for full-grid kernels (16384 blocks).
__device__ __forceinline__ int remap_idx() {
    int bid = blockIdx.x;
    int task = ((bid & 7) << 11) | (bid >> 3);
    return task * 256 + threadIdx.x;
}

__device__ __forceinline__ float rnd16(float v) { return (float)(f16)v; }

// INIT_FUSED: ldjac0 (sobel logdet series) + disp1 (corners from in-register
// 3x3 window, static-index selects). Writes packed record (disp1, ldjac0).
__global__ void __launch_bounds__(256) init_fused(const float* __restrict__ vel,
                                                  f16x4* __restrict__ rdst) {
    int idx = remap_idx();
    int n = idx >> 18;
    int rem = idx & (HW - 1);
    int y = rem >> 9, x = rem & (WW - 1);

    const float* v0 = vel + (size_t)n * 2 * HW;
    const float* v1 = v0 + HW;

    int ym = max(y - 1, 0), yp = min(y + 1, HH - 1);
    int xm = max(x - 1, 0), xp = min(x + 1, WW - 1);
    int r0 = ym * WW, r1 = y * WW, r2 = yp * WW;

    float A00 = v0[r0 + xm], A01 = v0[r0 + x], A02 = v0[r0 + xp];
    float A10 = v0[r1 + xm], A11 = v0[r1 + x], A12 = v0[r1 + xp];
    float A20 = v0[r2 + xm], A21 = v0[r2 + x], A22 = v0[r2 + xp];
    float B00 = v1[r0 + xm], B01 = v1[r0 + x], B02 = v1[r0 + xp];
    float B10 = v1[r1 + xm], B11 = v1[r1 + x], B12 = v1[r1 + xp];
    float B20 = v1[r2 + xm], B21 = v1[r2 + x], B22 = v1[r2 + xp];

    float a = 0.125f * ((A20 + 2.0f * A21 + A22) - (A00 + 2.0f * A01 + A02));
    float b = 0.125f * ((A02 + 2.0f * A12 + A22) - (A00 + 2.0f * A10 + A20));
    float c = 0.125f * ((B20 + 2.0f * B21 + B22) - (B00 + 2.0f * B01 + B02));
    float d = 0.125f * ((B02 + 2.0f * B12 + B22) - (B00 + 2.0f * B10 + B20));

    float xa = a, xb = b, xc = c, xd = d;
    float ld = EPS * (xa + xd);
    float na = xa * a + xb * c, nb = xa * b + xb * d;
    float nc = xc * a + xd * c, nd = xc * b + xd * d;
    xa = na; xb = nb; xc = nc; xd = nd;
    ld -= (EPS * EPS) * (xa + xd) * 0.5f;
    na = xa * a + xb * c; nb = xa * b + xb * d;
    nc = xc * a + xd * c; nd = xc * b + xd * d;
    xa = na; xb = nb; xc = nc; xd = nd;
    ld += (EPS * EPS * EPS) * (xa + xd) * (1.0f / 3.0f);
    na = xa * a + xb * c;
    nd = xc * b + xd * d;
    ld -= (EPS * EPS * EPS * EPS) * (na + nd) * 0.25f;

    float d0 = rnd16(EPS * A11);
    float d1 = rnd16(EPS * B11);

    float sy = fmaf((float)y + d0, SC, -0.5f);
    float sx = fmaf((float)x + d1, SC, -0.5f);
    SampC s = make_sampc(sy, sx);

    bool rlo = (sy < (float)y);
    bool clo = (sx < (float)x);

    float Ar0c0 = rlo ? A00 : A10, Ar0c1 = rlo ? A01 : A11, Ar0c2 = rlo ? A02 : A12;
    float Ar1c0 = rlo ? A10 : A20, Ar1c1 = rlo ? A11 : A21, Ar1c2 = rlo ? A12 : A22;
    float Br0c0 = rlo ? B00 : B10, Br0c1 = rlo ? B01 : B11, Br0c2 = rlo ? B02 : B12;
    float Br1c0 = rlo ? B10 : B20, Br1c1 = rlo ? B11 : B21, Br1c2 = rlo ? B12 : B22;

    float g00x = rnd16(EPS * (clo ? Ar0c0 : Ar0c1));
    float g01x = rnd16(EPS * (clo ? Ar0c1 : Ar0c2));
    float g10x = rnd16(EPS * (clo ? Ar1c0 : Ar1c1));
    float g11x = rnd16(EPS * (clo ? Ar1c1 : Ar1c2));
    float g00y = rnd16(EPS * (clo ? Br0c0 : Br0c1));
    float g01y = rnd16(EPS * (clo ? Br0c1 : Br0c2));
    float g10y = rnd16(EPS * (clo ? Br1c0 : Br1c1));
    float g11y = rnd16(EPS * (clo ? Br1c1 : Br1c2));

    float nd0 = d0 + s.w00 * g00x + s.w01 * g01x + s.w10 * g10x + s.w11 * g11x;
    float nd1 = d1 + s.w00 * g00y + s.w01 * g01y + s.w10 * g10y + s.w11 * g11y;

    f16x4 rec;
    rec.x = (f16)nd0; rec.y = (f16)nd1; rec.z = (f16)ld; rec.w = (f16)0.0f;
    rdst[(size_t)n * HW + rem] = rec;
}

// STEP-PAIR: two decoupled steps, block-local via LDS time-tiling.
// CW x CH core tile; R1 = step-k gather reach, R2 = step-(k+1) gather reach.
// IN  holds ext tile (core + R1+R2 halo); MID holds step-k output (core + R2).
template <int CW, int CH, int R1, int R2>
__global__ void __launch_bounds__(256) step_pair(const f16x4* __restrict__ rsrc,
                                                 f16x4* __restrict__ rdst) {
    constexpr int MW = CW + 2 * R2, MH = CH + 2 * R2;
    constexpr int EW = CW + 2 * (R1 + R2), EH = CH + 2 * (R1 + R2);
    __shared__ f16x4 IN[EH][EW + 1];
    __shared__ f16x4 MID[MH][MW + 1];

    int b = blockIdx.x;
    int xcd = b & 7, sub = b >> 3;
    constexpr int TPI = (512 / CW) * (512 / CH);  // tiles per image
    int img = 2 * xcd + (sub >= TPI ? 1 : 0);
    int tile = (sub >= TPI) ? sub - TPI : sub;
    int tx0 = (tile % (512 / CW)) * CW;
    int ty0 = (tile / (512 / CW)) * CH;

    const f16x4* rp = rsrc + (size_t)img * HW;
    int t = threadIdx.x;

    // phase 0: load ext tile (replicate-clamped at image borders)
    for (int i = t; i < EH * EW; i += 256) {
        int ey = i / EW, ex = i - ey * EW;
        int iy = min(max(ty0 - (R1 + R2) + ey, 0), HH - 1);
        int ix = min(max(tx0 - (R1 + R2) + ex, 0), WW - 1);
        IN[ey][ex] = rp[iy * WW + ix];
    }
    __syncthreads();

    // phase 1: step k on core + R2 margin (gathers from IN)
    {
        const int oy = ty0 - (R1 + R2), ox = tx0 - (R1 + R2);
        for (int i = t; i < MH * MW; i += 256) {
            int my = i / MW, mx = i - my * MW;
            int qy = ty0 - R2 + my, qx = tx0 - R2 + mx;
            f16x4 rv = IN[my + R1][mx + R1];
            float sy = fmaf((float)qy + (float)rv.x, SC, -0.5f);
            float sx = fmaf((float)qx + (float)rv.y, SC, -0.5f);
            SampC s = make_sampc(sy, sx);
            f16x4 g00 = IN[s.yc0 - oy][s.xc0 - ox];
            f16x4 g01 = IN[s.yc0 - oy][s.xc1 - ox];
            f16x4 g10 = IN[s.yc1 - oy][s.xc0 - ox];
            f16x4 g11 = IN[s.yc1 - oy][s.xc1 - ox];
            MID[my][mx] = step_rec(rv, g00, g01, g10, g11, s);
        }
    }
    __syncthreads();

    // phase 2: step k+1 on core (gathers from MID), write global
    {
        const int oy = ty0 - R2, ox = tx0 - R2;
        f16x4* wp = rdst + (size_t)img * HW;
        for (int i = t; i < CH * CW; i += 256) {
            int cy = i / CW, cx = i - cy * CW;
            int qy = ty0 + cy, qx = tx0 + cx;
            f16x4 rv = MID[cy + R2][cx + R2];
            float sy = fmaf((float)qy + (float)rv.x, SC, -0.5f);
            float sx = fmaf((float)qx + (float)rv.y, SC, -0.5f);
            SampC s = make_sampc(sy, sx);
            f16x4 g00 = MID[s.yc0 - oy][s.xc0 - ox];
            f16x4 g01 = MID[s.yc0 - oy][s.xc1 - ox];
            f16x4 g10 = MID[s.yc1 - oy][s.xc0 - ox];
            f16x4 g11 = MID[s.yc1 - oy][s.xc1 - ox];
            wp[qy * WW + qx] = step_rec(rv, g00, g01, g10, g11, s);
        }
    }
}

// FINAL: ldjac update #7 using streamed disp_7 (records hold disp_7, ldjac_6),
// writes planar f32 disp_7 and f32 ldjac_7.
__global__ void __launch_bounds__(256) step_final(const f16x4* __restrict__ rsrc,
                                                  float* __restrict__ doutp,
                                                  float* __restrict__ loutp) {
    int idx = remap_idx();
    int n = idx >> 18;
    int rem = idx & (HW - 1);
    int y = rem >> 9, x = rem & (WW - 1);

    const f16x4* rp = rsrc + (size_t)n * HW;

    f16x4 rv = rp[rem];
    float d0 = (float)rv.x, d1 = (float)rv.y, l = (float)rv.z;

    float sy = fmaf((float)y + d0, SC, -0.5f);
    float sx = fmaf((float)x + d1, SC, -0.5f);
    SampC s = make_sampc(sy, sx);

    f16x4 g00 = rp[s.yc0 * WW + s.xc0], g01 = rp[s.yc0 * WW + s.xc1];
    f16x4 g10 = rp[s.yc1 * WW + s.xc0], g11 = rp[s.yc1 * WW + s.xc1];

    float nl = l + s.w00 * (float)g00.z + s.w01 * (float)g01.z
                 + s.w10 * (float)g10.z + s.w11 * (float)g11.z;

    float* pd = doutp + (size_t)n * 2 * HW;
    pd[rem]      = d0;
    pd[HW + rem] = d1;
    loutp[(size_t)n * HW + rem] = nl;
}

extern "C" void kernel_launch(void* const* d_in, const int* in_sizes, int n_in,
                              void* d_out, int out_size, void* d_ws, size_t ws_size,
                              hipStream_t stream) {
    const float* vel = (const float*)d_in[0];
    float* out = (float*)d_out;

    f16x4* rA = (f16x4*)d_out;   // raw scratch (32MB of 48MB)
    f16x4* rB = (f16x4*)d_ws;    // raw scratch (32MB of 48MB)

    dim3 block(256);

    // INIT -> A (disp1, ldjac0)
    init_fused<<<dim3(TOT / 256), block, 0, stream>>>(vel, rA);
    // P1 = (K2,K3): A -> B   (disp3, ldjac2); gathers disp1/disp2 -> R=2/2
    step_pair<64, 64, 2, 2><<<dim3(1024), block, 0, stream>>>(rA, rB);
    // P2 = (K4,K5): B -> A   (disp5, ldjac4); gathers disp3/disp4 -> R=2/2
    step_pair<64, 64, 2, 2><<<dim3(1024), block, 0, stream>>>(rB, rA);
    // P3 = (K6,K7): A -> B   (disp7, ldjac6); gathers disp5/disp6 -> R=3/4
    step_pair<64, 32, 3, 4><<<dim3(2048), block, 0, stream>>>(rA, rB);
    // FINAL: B -> d_out planar (disp7 f32, ldjac7 f32); B=ws so no aliasing
    step_final<<<dim3(TOT / 256), block, 0, stream>>>(rB, out, out + DISP_ELEMS);
}

// Round 17
// 120.563 us; speedup vs baseline: 1.2351x; 1.2351x over previous
//
#include <hip/hip_runtime.h>

// Integrator (scaling & squaring) for vel [16,2,512,512] f32, with logdet-Jacobian.
// ROUND-17 = round-16 step-pair LDS time-tiling with OCCUPANCY-SIZED tiles:
//   32x32 core (R16's 64x64 cost 84KB LDS -> 1 block/CU -> 12.5% occupancy, the
//   regression cause). P1/P2: 23.8KB -> 6 blk/CU (75%); P3: 30.4KB -> 5 blk/CU.
//   Halo reaches identical to R16's validated values (reach depends on |disp_k|
//   bound 2^k*eps*max|v|, not tile size): P1/P2 R1=R2=2, P3 R1=3,R2=4.
// Packed records rec=(disp.y, disp.x, ldjac, 0) f16x4.
// 5 dispatches: INIT_FUSED -> P1(K2K3) -> P2(K4K5) -> P3(K6K7) -> FINAL.
// Buffers: rA = d_out raw (32MB), rB = ws. init->A, P1:A->B, P2:B->A, P3:A->B,
// FINAL: B -> planar f32 d_out (B=ws, no aliasing).

#define NB 16
#define HH 512
#define WW 512
#define HW (HH * WW)          // 262144 = 1<<18
#define TOT (NB * HW)         // 4194304
#define EPS 0.0078125f        // 2^-7
#define DISP_ELEMS (NB * 2 * HW)
#define SC (512.0f / 511.0f)

typedef _Float16 f16;
typedef _Float16 f16x4 __attribute__((ext_vector_type(4)));

struct SampC {
    int yc0, xc0, yc1, xc1;   // clamped corner coords (global)
    float w00, w01, w10, w11; // bilinear weights, OOB folded to 0
};

__device__ __forceinline__ SampC make_sampc(float sy, float sx) {
    float fy = floorf(sy), fx = floorf(sx);
    float wy = sy - fy, wx = sx - fx;
    int y0 = (int)fy, x0 = (int)fx;
    int y1 = y0 + 1, x1 = x0 + 1;
    bool xv0 = (unsigned)x0 < (unsigned)WW;
    bool xv1 = (unsigned)x1 < (unsigned)WW;
    bool yv0 = (unsigned)y0 < (unsigned)HH;
    bool yv1 = (unsigned)y1 < (unsigned)HH;
    SampC s;
    s.xc0 = min(max(x0, 0), WW - 1); s.xc1 = min(max(x1, 0), WW - 1);
    s.yc0 = min(max(y0, 0), HH - 1); s.yc1 = min(max(y1, 0), HH - 1);
    float omwx = 1.0f - wx, omwy = 1.0f - wy;
    s.w00 = (xv0 && yv0) ? omwx * omwy : 0.0f;
    s.w01 = (xv1 && yv0) ? wx * omwy   : 0.0f;
    s.w10 = (xv0 && yv1) ? omwx * wy   : 0.0f;
    s.w11 = (xv1 && yv1) ? wx * wy     : 0.0f;
    return s;
}

__device__ __forceinline__ f16x4 step_rec(f16x4 rv, f16x4 g00, f16x4 g01,
                                          f16x4 g10, f16x4 g11, const SampC& s) {
    float d0 = (float)rv.x, d1 = (float)rv.y, l = (float)rv.z;
    float nd0 = d0 + s.w00 * (float)g00.x + s.w01 * (float)g01.x
                   + s.w10 * (float)g10.x + s.w11 * (float)g11.x;
    float nd1 = d1 + s.w00 * (float)g00.y + s.w01 * (float)g01.y
                   + s.w10 * (float)g10.y + s.w11 * (float)g11.y;
    float nl  = l  + s.w00 * (float)g00.z + s.w01 * (float)g01.z
                   + s.w10 * (float)g10.z + s.w11 * (float)g11.z;
    f16x4 w; w.x = (f16)nd0; w.y = (f16)nd1; w.z = (f16)nl; w.w = (f16)0.0f;
    return w;
}

// XCD-remapped index for full-grid kernels (16384 blocks).
__device__ __forceinline__ int remap_idx() {
    int bid = blockIdx.x;
    int task = ((bid & 7) << 11) | (bid >> 3);
    return task * 256 + threadIdx.x;
}

__device__ __forceinline__ float rnd16(float v) { return (float)(f16)v; }

// INIT_FUSED: ldjac0 (sobel logdet series) + disp1 (corners from in-register
// 3x3 window, static-index selects). Writes packed record (disp1, ldjac0).
__global__ void __launch_bounds__(256) init_fused(const float* __restrict__ vel,
                                                  f16x4* __restrict__ rdst) {
    int idx = remap_idx();
    int n = idx >> 18;
    int rem = idx & (HW - 1);
    int y = rem >> 9, x = rem & (WW - 1);

    const float* v0 = vel + (size_t)n * 2 * HW;
    const float* v1 = v0 + HW;

    int ym = max(y - 1, 0), yp = min(y + 1, HH - 1);
    int xm = max(x - 1, 0), xp = min(x + 1, WW - 1);
    int r0 = ym * WW, r1 = y * WW, r2 = yp * WW;

    float A00 = v0[r0 + xm], A01 = v0[r0 + x], A02 = v0[r0 + xp];
    float A10 = v0[r1 + xm], A11 = v0[r1 + x], A12 = v0[r1 + xp];
    float A20 = v0[r2 + xm], A21 = v0[r2 + x], A22 = v0[r2 + xp];
    float B00 = v1[r0 + xm], B01 = v1[r0 + x], B02 = v1[r0 + xp];
    float B10 = v1[r1 + xm], B11 = v1[r1 + x], B12 = v1[r1 + xp];
    float B20 = v1[r2 + xm], B21 = v1[r2 + x], B22 = v1[r2 + xp];

    float a = 0.125f * ((A20 + 2.0f * A21 + A22) - (A00 + 2.0f * A01 + A02));
    float b = 0.125f * ((A02 + 2.0f * A12 + A22) - (A00 + 2.0f * A10 + A20));
    float c = 0.125f * ((B20 + 2.0f * B21 + B22) - (B00 + 2.0f * B01 + B02));
    float d = 0.125f * ((B02 + 2.0f * B12 + B22) - (B00 + 2.0f * B10 + B20));

    float xa = a, xb = b, xc = c, xd = d;
    float ld = EPS * (xa + xd);
    float na = xa * a + xb * c, nb = xa * b + xb * d;
    float nc = xc * a + xd * c, nd = xc * b + xd * d;
    xa = na; xb = nb; xc = nc; xd = nd;
    ld -= (EPS * EPS) * (xa + xd) * 0.5f;
    na = xa * a + xb * c; nb = xa * b + xb * d;
    nc = xc * a + xd * c; nd = xc * b + xd * d;
    xa = na; xb = nb; xc = nc; xd = nd;
    ld += (EPS * EPS * EPS) * (xa + xd) * (1.0f / 3.0f);
    na = xa * a + xb * c;
    nd = xc * b + xd * d;
    ld -= (EPS * EPS * EPS * EPS) * (na + nd) * 0.25f;

    float d0 = rnd16(EPS * A11);
    float d1 = rnd16(EPS * B11);

    float sy = fmaf((float)y + d0, SC, -0.5f);
    float sx = fmaf((float)x + d1, SC, -0.5f);
    SampC s = make_sampc(sy, sx);

    bool rlo = (sy < (float)y);
    bool clo = (sx < (float)x);

    float Ar0c0 = rlo ? A00 : A10, Ar0c1 = rlo ? A01 : A11, Ar0c2 = rlo ? A02 : A12;
    float Ar1c0 = rlo ? A10 : A20, Ar1c1 = rlo ? A11 : A21, Ar1c2 = rlo ? A12 : A22;
    float Br0c0 = rlo ? B00 : B10, Br0c1 = rlo ? B01 : B11, Br0c2 = rlo ? B02 : B12;
    float Br1c0 = rlo ? B10 : B20, Br1c1 = rlo ? B11 : B21, Br1c2 = rlo ? B12 : B22;

    float g00x = rnd16(EPS * (clo ? Ar0c0 : Ar0c1));
    float g01x = rnd16(EPS * (clo ? Ar0c1 : Ar0c2));
    float g10x = rnd16(EPS * (clo ? Ar1c0 : Ar1c1));
    float g11x = rnd16(EPS * (clo ? Ar1c1 : Ar1c2));
    float g00y = rnd16(EPS * (clo ? Br0c0 : Br0c1));
    float g01y = rnd16(EPS * (clo ? Br0c1 : Br0c2));
    float g10y = rnd16(EPS * (clo ? Br1c0 : Br1c1));
    float g11y = rnd16(EPS * (clo ? Br1c1 : Br1c2));

    float nd0 = d0 + s.w00 * g00x + s.w01 * g01x + s.w10 * g10x + s.w11 * g11x;
    float nd1 = d1 + s.w00 * g00y + s.w01 * g01y + s.w10 * g10y + s.w11 * g11y;

    f16x4 rec;
    rec.x = (f16)nd0; rec.y = (f16)nd1; rec.z = (f16)ld; rec.w = (f16)0.0f;
    rdst[(size_t)n * HW + rem] = rec;
}

// STEP-PAIR: two decoupled steps, block-local via LDS time-tiling.
// CW x CH core tile; R1 = step-k gather reach, R2 = step-(k+1) gather reach.
template <int CW, int CH, int R1, int R2>
__global__ void __launch_bounds__(256) step_pair(const f16x4* __restrict__ rsrc,
                                                 f16x4* __restrict__ rdst) {
    constexpr int MW = CW + 2 * R2, MH = CH + 2 * R2;
    constexpr int EW = CW + 2 * (R1 + R2), EH = CH + 2 * (R1 + R2);
    __shared__ f16x4 IN[EH][EW + 1];
    __shared__ f16x4 MID[MH][MW + 1];

    int b = blockIdx.x;
    int xcd = b & 7, sub = b >> 3;               // sub in [0, 2*TPI)
    constexpr int TPI = (512 / CW) * (512 / CH); // tiles per image
    int img = 2 * xcd + (sub >= TPI ? 1 : 0);
    int tile = (sub >= TPI) ? sub - TPI : sub;
    int tx0 = (tile % (512 / CW)) * CW;
    int ty0 = (tile / (512 / CW)) * CH;

    const f16x4* rp = rsrc + (size_t)img * HW;
    int t = threadIdx.x;

    // phase 0: load ext tile (replicate-clamped at image borders)
    for (int i = t; i < EH * EW; i += 256) {
        int ey = i / EW, ex = i - ey * EW;
        int iy = min(max(ty0 - (R1 + R2) + ey, 0), HH - 1);
        int ix = min(max(tx0 - (R1 + R2) + ex, 0), WW - 1);
        IN[ey][ex] = rp[iy * WW + ix];
    }
    __syncthreads();

    // phase 1: step k on core + R2 margin (gathers from IN)
    {
        const int oy = ty0 - (R1 + R2), ox = tx0 - (R1 + R2);
        for (int i = t; i < MH * MW; i += 256) {
            int my = i / MW, mx = i - my * MW;
            int qy = ty0 - R2 + my, qx = tx0 - R2 + mx;
            f16x4 rv = IN[my + R1][mx + R1];
            float sy = fmaf((float)qy + (float)rv.x, SC, -0.5f);
            float sx = fmaf((float)qx + (float)rv.y, SC, -0.5f);
            SampC s = make_sampc(sy, sx);
            f16x4 g00 = IN[s.yc0 - oy][s.xc0 - ox];
            f16x4 g01 = IN[s.yc0 - oy][s.xc1 - ox];
            f16x4 g10 = IN[s.yc1 - oy][s.xc0 - ox];
            f16x4 g11 = IN[s.yc1 - oy][s.xc1 - ox];
            MID[my][mx] = step_rec(rv, g00, g01, g10, g11, s);
        }
    }
    __syncthreads();

    // phase 2: step k+1 on core (gathers from MID), write global
    {
        const int oy = ty0 - R2, ox = tx0 - R2;
        f16x4* wp = rdst + (size_t)img * HW;
        for (int i = t; i < CH * CW; i += 256) {
            int cy = i / CW, cx = i - cy * CW;
            int qy = ty0 + cy, qx = tx0 + cx;
            f16x4 rv = MID[cy + R2][cx + R2];
            float sy = fmaf((float)qy + (float)rv.x, SC, -0.5f);
            float sx = fmaf((float)qx + (float)rv.y, SC, -0.5f);
            SampC s = make_sampc(sy, sx);
            f16x4 g00 = MID[s.yc0 - oy][s.xc0 - ox];
            f16x4 g01 = MID[s.yc0 - oy][s.xc1 - ox];
            f16x4 g10 = MID[s.yc1 - oy][s.xc0 - ox];
            f16x4 g11 = MID[s.yc1 - oy][s.xc1 - ox];
            wp[qy * WW + qx] = step_rec(rv, g00, g01, g10, g11, s);
        }
    }
}

// FINAL: ldjac update #7 using streamed disp_7 (records hold disp_7, ldjac_6),
// writes planar f32 disp_7 and f32 ldjac_7.
__global__ void __launch_bounds__(256) step_final(const f16x4* __restrict__ rsrc,
                                                  float* __restrict__ doutp,
                                                  float* __restrict__ loutp) {
    int idx = remap_idx();
    int n = idx >> 18;
    int rem = idx & (HW - 1);
    int y = rem >> 9, x = rem & (WW - 1);

    const f16x4* rp = rsrc + (size_t)n * HW;

    f16x4 rv = rp[rem];
    float d0 = (float)rv.x, d1 = (float)rv.y, l = (float)rv.z;

    float sy = fmaf((float)y + d0, SC, -0.5f);
    float sx = fmaf((float)x + d1, SC, -0.5f);
    SampC s = make_sampc(sy, sx);

    f16x4 g00 = rp[s.yc0 * WW + s.xc0], g01 = rp[s.yc0 * WW + s.xc1];
    f16x4 g10 = rp[s.yc1 * WW + s.xc0], g11 = rp[s.yc1 * WW + s.xc1];

    float nl = l + s.w00 * (float)g00.z + s.w01 * (float)g01.z
                 + s.w10 * (float)g10.z + s.w11 * (float)g11.z;

    float* pd = doutp + (size_t)n * 2 * HW;
    pd[rem]      = d0;
    pd[HW + rem] = d1;
    loutp[(size_t)n * HW + rem] = nl;
}

extern "C" void kernel_launch(void* const* d_in, const int* in_sizes, int n_in,
                              void* d_out, int out_size, void* d_ws, size_t ws_size,
                              hipStream_t stream) {
    const float* vel = (const float*)d_in[0];
    float* out = (float*)d_out;

    f16x4* rA = (f16x4*)d_out;   // raw scratch (32MB of 48MB)
    f16x4* rB = (f16x4*)d_ws;    // raw scratch (32MB of 48MB)

    dim3 block(256);

    // INIT -> A (disp1, ldjac0)
    init_fused<<<dim3(TOT / 256), block, 0, stream>>>(vel, rA);
    // 16 img x 256 tiles = 4096 blocks per pair
    // P1 = (K2,K3): A -> B   gathers disp1/disp2 -> R=2/2 ; 23.8KB LDS, 6 blk/CU
    step_pair<32, 32, 2, 2><<<dim3(4096), block, 0, stream>>>(rA, rB);
    // P2 = (K4,K5): B -> A   gathers disp3/disp4 -> R=2/2
    step_pair<32, 32, 2, 2><<<dim3(4096), block, 0, stream>>>(rB, rA);
    // P3 = (K6,K7): A -> B   gathers disp5/disp6 -> R=3/4 ; 30.4KB LDS, 5 blk/CU
    step_pair<32, 32, 3, 4><<<dim3(4096), block, 0, stream>>>(rA, rB);
    // FINAL: B -> d_out planar (disp7 f32, ldjac7 f32); B=ws so no aliasing
    step_final<<<dim3(TOT / 256), block, 0, stream>>>(rB, out, out + DISP_ELEMS);
}